// Round 1
// baseline (39.869 us; speedup 1.0000x reference)
//
#include <hip/hip_runtime.h>
#include <math.h>

#define RPOOL 5

__global__ __launch_bounds__(256, 8)
void minmax_pool_sort_kernel(const float* __restrict__ x,
                             const int* __restrict__ lengths,
                             float* __restrict__ out,
                             int n, int L) {
    const int wave_in_block = threadIdx.x >> 6;
    const int lane = threadIdx.x & 63;
    const int row = blockIdx.x * 4 + wave_in_block;
    if (row >= n) return;

    const int l = lengths[row];
    const float* xr = x + (long long)row * L;

    float vals[2 * RPOOL];

#pragma unroll
    for (int j = 0; j < RPOOL; ++j) {
        const int s = (j * l) / RPOOL;                       // floor(j*l/R)
        const int e = ((j + 1) * l + RPOOL - 1) / RPOOL;     // ceil((j+1)*l/R)
        float mx = -INFINITY;
        float mn = INFINITY;
        for (int t = s + lane; t < e; t += 64) {
            float v = xr[t];
            mx = fmaxf(mx, v);
            mn = fminf(mn, v);
        }
        // 64-lane butterfly reduction (all lanes end with the result)
#pragma unroll
        for (int off = 32; off > 0; off >>= 1) {
            mx = fmaxf(mx, __shfl_xor(mx, off, 64));
            mn = fminf(mn, __shfl_xor(mn, off, 64));
        }
        vals[j] = mx;
        vals[RPOOL + j] = mn;
    }

    // Sort 10 values ascending: fully-unrolled bubble sorting network
    // (static indices only -> stays in registers).
#pragma unroll
    for (int i = 0; i < 2 * RPOOL - 1; ++i) {
#pragma unroll
        for (int k = 0; k < 2 * RPOOL - 1 - i; ++k) {
            const float a = vals[k];
            const float b = vals[k + 1];
            vals[k]     = fminf(a, b);
            vals[k + 1] = fmaxf(a, b);
        }
    }

    if (lane == 0) {
        float* o = out + (long long)row * (2 * RPOOL);
#pragma unroll
        for (int k = 0; k < 2 * RPOOL; ++k) o[k] = vals[k];
    }
}

extern "C" void kernel_launch(void* const* d_in, const int* in_sizes, int n_in,
                              void* d_out, int out_size, void* d_ws, size_t ws_size,
                              hipStream_t stream) {
    const float* x       = (const float*)d_in[0];
    const int*   lengths = (const int*)d_in[1];
    float*       out     = (float*)d_out;

    const int n = in_sizes[1];            // N rows
    const int L = in_sizes[0] / n;        // row stride (1000)

    const int blocks = (n + 3) / 4;       // 4 waves (rows) per 256-thread block
    hipLaunchKernelGGL(minmax_pool_sort_kernel, dim3(blocks), dim3(256), 0, stream,
                       x, lengths, out, n, L);
}

// Round 3
// 30.801 us; speedup vs baseline: 1.2944x; 1.2944x over previous
//
#include <hip/hip_runtime.h>
#include <math.h>

#define RPOOL 5

__global__ __launch_bounds__(256, 4)
void minmax_pool_sort_kernel(const float* __restrict__ x,
                             const int* __restrict__ lengths,
                             float* __restrict__ out,
                             int n, int L) {
    const int lane = threadIdx.x & 63;
    const int row  = blockIdx.x * 4 + (threadIdx.x >> 6);
    if (row >= n) return;

    // l is wave-uniform: force it to an SGPR so boundary math runs on the SALU.
    const int l = __builtin_amdgcn_readfirstlane(lengths[row]);
    const float* xr = x + (long long)row * L;

    // Window boundaries (scalar math, magic-mul divide by 5).
    int s[RPOOL], e[RPOOL];
#pragma unroll
    for (int j = 0; j < RPOOL; ++j) {
        s[j] = (j * l) / RPOOL;                      // floor(j*l/R)
        e[j] = ((j + 1) * l + RPOOL - 1) / RPOOL;    // ceil((j+1)*l/R)
    }

    // Max window size = ceil(1000/5)+1 = 201 elems <= 51 float4s <= 64 lanes:
    // ONE aligned float4 load per window covers it. Issue all 5 loads upfront
    // (independent -> single latency exposure).
    float4 v[RPOOL];
    int    t0[RPOOL];
#pragma unroll
    for (int j = 0; j < RPOOL; ++j) {
        const int sa = s[j] & ~3;          // 16B-aligned start (row base is 16B-aligned)
        const int t  = sa + lane * 4;
        t0[j] = t;
        // Lanes past the window clamp to row start (in-bounds); masked below.
        const int idx = (t < e[j]) ? t : 0;
        v[j] = *reinterpret_cast<const float4*>(xr + idx);
    }

    float vals[2 * RPOOL];
#pragma unroll
    for (int j = 0; j < RPOOL; ++j) {
        const float vv0 = v[j].x, vv1 = v[j].y, vv2 = v[j].z, vv3 = v[j].w;
        float m0, m1, m2, m3, n0, n1, n2, n3;
        {
            const int t = t0[j];
            const bool ok0 = (t     >= s[j]) & (t     < e[j]);
            const bool ok1 = (t + 1 >= s[j]) & (t + 1 < e[j]);
            const bool ok2 = (t + 2 >= s[j]) & (t + 2 < e[j]);
            const bool ok3 = (t + 3 >= s[j]) & (t + 3 < e[j]);
            m0 = ok0 ? vv0 : -INFINITY;  n0 = ok0 ? vv0 : INFINITY;
            m1 = ok1 ? vv1 : -INFINITY;  n1 = ok1 ? vv1 : INFINITY;
            m2 = ok2 ? vv2 : -INFINITY;  n2 = ok2 ? vv2 : INFINITY;
            m3 = ok3 ? vv3 : -INFINITY;  n3 = ok3 ? vv3 : INFINITY;
        }
        float mx = fmaxf(fmaxf(m0, m1), fmaxf(m2, m3));
        float mn = fminf(fminf(n0, n1), fminf(n2, n3));

        // 64-lane butterfly reduce (all lanes end with the result).
#pragma unroll
        for (int off = 32; off > 0; off >>= 1) {
            mx = fmaxf(mx, __shfl_xor(mx, off, 64));
            mn = fminf(mn, __shfl_xor(mn, off, 64));
        }
        vals[j]         = mx;
        vals[RPOOL + j] = mn;
    }

    // Sort 10 values ascending — fully-unrolled bubble network (known correct,
    // static register indices only).
#pragma unroll
    for (int i = 0; i < 2 * RPOOL - 1; ++i) {
#pragma unroll
        for (int k = 0; k < 2 * RPOOL - 1 - i; ++k) {
            const float a = vals[k];
            const float b = vals[k + 1];
            vals[k]     = fminf(a, b);
            vals[k + 1] = fmaxf(a, b);
        }
    }

    // Coalesced store: lanes 0..9 each store one value (single 40B transaction).
    float ov = vals[0];
#pragma unroll
    for (int k = 1; k < 2 * RPOOL; ++k) ov = (lane == k) ? vals[k] : ov;
    if (lane < 2 * RPOOL) out[(long long)row * (2 * RPOOL) + lane] = ov;
}

extern "C" void kernel_launch(void* const* d_in, const int* in_sizes, int n_in,
                              void* d_out, int out_size, void* d_ws, size_t ws_size,
                              hipStream_t stream) {
    const float* x       = (const float*)d_in[0];
    const int*   lengths = (const int*)d_in[1];
    float*       out     = (float*)d_out;

    const int n = in_sizes[1];            // N rows
    const int L = in_sizes[0] / n;        // row stride (1000)

    const int blocks = (n + 3) / 4;       // 4 waves (rows) per 256-thread block
    hipLaunchKernelGGL(minmax_pool_sort_kernel, dim3(blocks), dim3(256), 0, stream,
                       x, lengths, out, n, L);
}